// Round 6
// baseline (199.927 us; speedup 1.0000x reference)
//
#include <hip/hip_runtime.h>
#include <math.h>

#define ALPHA 0.466f
#define T_FRAMES 200
#define HOPW 120
#define NSAMP 24000
#define M1 40
#define HID 256
#define CONDW 192

// Chunked MLSA scan: each wave owns one (batch, 96-sample output window),
// 384 warm samples from zero state (transient < 0.03125 noise floor, r2).
// ONE WAVE PER BLOCK; 1000 blocks <= 1024 SIMDs. P/A filters on even/odd
// lanes. r5 lesson: per-sample time = serialized chain latencies in program
// order (in-order issue). This round: r4's affine split (S = SX + dl*CKp,
// bit-exact, verified) + EXPLICIT software pipeline -- SX for sample k+1 is
// computed between S(k)'s cross-lane issue and its consumption, so the
// glue's ~100cyc cross-lane latency is hidden under ~25 independent instrs.
#define WARMS 384
#define OUTS 96
#define SLOTS (NSAMP / OUTS)     // 250 per batch -> 1000 blocks

#define F8 8
#define EMB_BLOCKS (4 * T_FRAMES / F8)       // 100
#define BPF ((NSAMP + 255) / 256)            // 94

#if defined(__has_builtin)
#  if __has_builtin(__builtin_amdgcn_permlane32_swap)
#    define HAVE_PLSWAP 1
#  endif
#endif
#ifndef HAVE_PLSWAP
#  define HAVE_PLSWAP 0
#endif

// ---------------------------------------------------------------------------
// Kernel P: embed (blocks 0..99) U exc (blocks 100..851) in ONE dispatch.
// (unchanged)
// ---------------------------------------------------------------------------
__global__ __launch_bounds__(256) void prep_kernel(
    const float* __restrict__ mceps, const float* __restrict__ apdcs,
    const float* __restrict__ f0s, const float* __restrict__ noise,
    const float* __restrict__ Wm, const float* __restrict__ bm,
    const float* __restrict__ Wa, const float* __restrict__ ba,
    const float* __restrict__ Wf, const float* __restrict__ bf,
    const float* __restrict__ Wpa, const float* __restrict__ bpa,
    const float* __restrict__ Wpp, const float* __restrict__ bpp,
    const float* __restrict__ Wrp, const float* __restrict__ brp,
    const float* __restrict__ Wra, const float* __restrict__ bra,
    const float* __restrict__ Wap,
    float* __restrict__ bcoef, float* __restrict__ exc)
{
    const int tid = threadIdx.x;

    if (blockIdx.x >= EMB_BLOCKS) {
        const int xb = blockIdx.x - EMB_BLOCKS;
        const int ff = xb / BPF;
        const int n = (xb % BPF) * 256 + tid;

        if (ff >= 4) {
            if (n < NSAMP) exc[ff * NSAMP + n] = 0.5f * noise[(ff - 4) * NSAMP + n];
            return;
        }

        __shared__ double s_base[T_FRAMES];
        __shared__ double s_step[T_FRAMES];
        __shared__ float  s_amp[T_FRAMES];

        if (tid < 64) {
            const int L = tid;
            double st[4], loc[4];
            float am[4];
            double s = 0.0;
            #pragma unroll
            for (int j = 0; j < 4; ++j) {
                int ft = L * 4 + j;
                if (ft < T_FRAMES) {
                    double fv = exp((double)f0s[ff * T_FRAMES + ft] * 0.25 + 5.0);
                    st[j] = fv / 24000.0;
                    am[j] = (float)(0.5 * sqrt(24000.0 / fmax(fv, 1.0)));
                } else { st[j] = 0.0; am[j] = 0.f; }
                loc[j] = s;
                s += st[j];
            }
            double tot = s;
            #pragma unroll
            for (int off = 1; off < 64; off <<= 1) {
                double v = __shfl_up(s, off, 64);
                if (L >= off) s += v;
            }
            double excl = s - tot;
            #pragma unroll
            for (int j = 0; j < 4; ++j) {
                int ft = L * 4 + j;
                if (ft < T_FRAMES) {
                    s_base[ft] = 120.0 * (excl + loc[j]);
                    s_step[ft] = st[j];
                    s_amp[ft]  = am[j];
                }
            }
        }
        __syncthreads();

        if (n < NSAMP) {
            int ft = n / HOPW, k = n - ft * HOPW;
            double st = s_step[ft], bs = s_base[ft];
            double ph  = bs + (double)(k + 1) * st;
            double php = bs + (double)k * st;
            exc[ff * NSAMP + n] = (floor(ph) > floor(php)) ? s_amp[ft] : 0.0f;
        }
        return;
    }

    // =================== embed path (blocks 0..99) ===================
    __shared__ float s_mc[F8][M1];
    __shared__ float s_ap[F8][5];
    __shared__ float s_f0[F8];
    __shared__ float s_h[F8][HID];
    __shared__ float s_ca[F8][CONDW];
    __shared__ float s_cp[F8][CONDW];
    __shared__ float s_mcp[F8][M1];
    __shared__ float s_mca[F8][M1];

    const int R0 = blockIdx.x * F8;

    for (int j = tid; j < F8 * M1; j += 256) s_mc[j / M1][j % M1] = mceps[R0 * M1 + j];
    if (tid < F8 * 5) s_ap[tid / 5][tid % 5] = apdcs[R0 * 5 + tid];
    if (tid < F8)     s_f0[tid] = f0s[R0 + tid];
    __syncthreads();

    {
        float acc[F8];
        const float bias = bm[tid] + ba[tid] + bf[tid];
        #pragma unroll
        for (int r = 0; r < F8; ++r) acc[r] = bias;
        for (int k = 0; k < M1; ++k) {
            float w = Wm[k * HID + tid];
            #pragma unroll
            for (int r = 0; r < F8; ++r) acc[r] = fmaf(s_mc[r][k], w, acc[r]);
        }
        #pragma unroll
        for (int k = 0; k < 5; ++k) {
            float w = Wa[k * HID + tid];
            #pragma unroll
            for (int r = 0; r < F8; ++r) acc[r] = fmaf(s_ap[r][k], w, acc[r]);
        }
        float wf = Wf[tid];
        #pragma unroll
        for (int r = 0; r < F8; ++r) s_h[r][tid] = fmaf(s_f0[r], wf, acc[r]);
    }
    __syncthreads();

    if (tid < CONDW) {
        float aA[F8], aP[F8];
        #pragma unroll
        for (int r = 0; r < F8; ++r) { aA[r] = bpa[tid]; aP[r] = bpp[tid]; }
        for (int k = 0; k < HID; k += 4) {
            float4 h4[F8];
            #pragma unroll
            for (int r = 0; r < F8; ++r) h4[r] = *(const float4*)&s_h[r][k];
            #pragma unroll
            for (int kk = 0; kk < 4; ++kk) {
                float wa = Wpa[(k + kk) * CONDW + tid];
                float wp = Wpp[(k + kk) * CONDW + tid];
                #pragma unroll
                for (int r = 0; r < F8; ++r) {
                    float hv = (&h4[r].x)[kk];
                    aA[r] = fmaf(hv, wa, aA[r]);
                    aP[r] = fmaf(hv, wp, aP[r]);
                }
            }
        }
        #pragma unroll
        for (int r = 0; r < F8; ++r) { s_ca[r][tid] = aA[r]; s_cp[r][tid] = aP[r]; }
    }
    __syncthreads();

    if (tid < M1) {
        const int u = tid;
        float acc[F8];
        #pragma unroll
        for (int r = 0; r < F8; ++r) acc[r] = brp[u];
        for (int k = 0; k < CONDW; k += 4) {
            float4 c4[F8];
            #pragma unroll
            for (int r = 0; r < F8; ++r) c4[r] = *(const float4*)&s_cp[r][k];
            #pragma unroll
            for (int kk = 0; kk < 4; ++kk) {
                float w = Wrp[(k + kk) * M1 + u];
                #pragma unroll
                for (int r = 0; r < F8; ++r) acc[r] = fmaf((&c4[r].x)[kk], w, acc[r]);
            }
        }
        #pragma unroll
        for (int r = 0; r < F8; ++r)
            s_mcp[r][u] = s_mc[r][u] + 0.1f * tanhf(acc[r]);
    } else if (tid >= 64 && tid < 64 + M1) {
        const int u = tid - 64;
        float acc[F8];
        #pragma unroll
        for (int r = 0; r < F8; ++r) acc[r] = bra[u];
        for (int k = 0; k < CONDW; k += 4) {
            float4 c4[F8];
            #pragma unroll
            for (int r = 0; r < F8; ++r) c4[r] = *(const float4*)&s_ca[r][k];
            #pragma unroll
            for (int kk = 0; kk < 4; ++kk) {
                float w = Wra[(k + kk) * M1 + u];
                #pragma unroll
                for (int r = 0; r < F8; ++r) acc[r] = fmaf((&c4[r].x)[kk], w, acc[r]);
            }
        }
        #pragma unroll
        for (int r = 0; r < F8; ++r) {
            float aw = 0.f;
            #pragma unroll
            for (int j = 0; j < 5; ++j) aw = fmaf(s_ap[r][j], Wap[j * M1 + u], aw);
            s_mca[r][u] = s_mc[r][u] + 0.1f * tanhf(acc[r]) + aw;
        }
    }
    __syncthreads();

    if (tid < 16) {
        const int r = tid >> 1, path = tid & 1;
        const int R = R0 + r;
        const int batch = R / T_FRAMES, t = R - batch * T_FRAMES;
        const float* src = path ? s_mca[r] : s_mcp[r];
        float* dst = bcoef + ((path * 4 + batch) * T_FRAMES + t) * M1;
        float prev = src[M1 - 1];
        dst[M1 - 1] = prev;
        for (int m = M1 - 2; m >= 0; --m) {
            prev = src[m] - ALPHA * prev;
            dst[m] = prev;
        }
    }
}

// ---------------------------------------------------------------------------
// DPP helpers. row_shr:N = 0x110|N; row_bcast15 = 0x142.
// ---------------------------------------------------------------------------
template <int CTRL>
__device__ __forceinline__ float rshr(float x) {
    return __int_as_float(
        __builtin_amdgcn_mov_dpp(__float_as_int(x), CTRL, 0xF, 0xF, true));
}
__device__ __forceinline__ float rlane(float x, int l) {
    return __int_as_float(__builtin_amdgcn_readlane(__float_as_int(x), l));
}
// pin a wave-uniform value into a VGPR (DPP-fusable VOP2 forms need vsrc1=VGPR)
__device__ __forceinline__ float vpin(float x) {
    asm("" : "+v"(x));
    return x;
}

// ---------------------------------------------------------------------------
// Samples [ks, ke) of one frame, software-pipelined one sample deep.
// Pipeline registers (carried): uP0..uP3, XP, XSP (B-independent, carry
// across frames) and SXP (B-dependent; caller refreshes per frame).
// Per body: S(k) = fma(dl, CKp, SXP) issues its cross-lane consumers
// immediately; stage-1 + E-completion + the whole SX-work for k+1 fill the
// latency; glue consumes last. All arithmetic bit-identical to r4 (passed).
// ---------------------------------------------------------------------------
__device__ __forceinline__ void run_frame(
    const float* __restrict__ sx, float AB,
    float BP1, float BP2, float BP3, float BP4,
    float B0, float B1, float B2, float B3, float B4,
    float GB, float CKp, float K, float KS, float IPw,
    bool pos0, bool row0, bool parodd,
    float& uP0, float& uP1, float& uP2, float& uP3,
    float& XP, float& XSP, float& SXP,
    float& dlp, float& xin,
    float& m1, float& m2, float& m3, float& m4, float& w0,
    float* __restrict__ yb, int ks, int ke)
{
    const float A   = ALPHA;
    const float AA  = 1.0f - A * A;
    const float A2  = A * A;
    const float mA3 = -(A * A2);
    const float A4  = A2 * A2;
    const float R   = -(A4 * A);     // (-A)^5 : inter-position ratio
    const float R2  = R * R;

    const float Rv   = vpin(R);
    const float R2v  = vpin(R2);
    const float IPwv = vpin(IPw);

    #pragma unroll 1
    for (int k8 = ks; k8 < ke; k8 += 8) {
        const float4 g0 = *(const float4*)&sx[k8];
        const float4 g1 = *(const float4*)&sx[k8 + 4];
        const float xs[8] = {g0.x, g0.y, g0.z, g0.w, g1.x, g1.y, g1.z, g1.w};
        #pragma unroll
        for (int j = 0; j < 8; ++j) {
            float x = xs[j];                           // G pre-folded

            // ---- carried-chain head ----
            float dl = fmaf(AA, xin, A * dlp);
            float S  = fmaf(dl, CKp, SXP);

            // ---- issue S's cross-lane consumers NOW (latency starts) ----
            float Sx  = rshr<0x111>(S);
            float TT1 = rshr<0x142>(S);
            float TT0 = rshr<0x142>(Sx);
#if HAVE_PLSWAP
            typedef unsigned u32x2 __attribute__((ext_vector_type(2)));
            u32x2 rr = __builtin_amdgcn_permlane32_swap(
                __float_as_uint(S), __float_as_uint(S), false, false);
#endif

            // ---- filler 1: stage 1 (independent; y1 = x + 2p exact) ----
            float na0 = fmaf(A, m1, AA * w0);
            float na1 = fmaf(A, m2, AB * m1);
            float na2 = fmaf(A, m3, AB * m2);
            float na3 = fmaf(A, m4, AB * m3);
            float p = fmaf(na2, BP3, na0 * BP1);
            float q = fmaf(na3, BP4, na1 * BP2);
            float x1 = x + (p - q);
            float y1 = fmaf(2.0f, p, x);
            m1 = na0; m2 = na1; m3 = na2; m4 = na3; w0 = x1;

            // ---- filler 2: E-completion for sample k ----
            float Si = fmaf(KS, dl, XSP);   // bit-exact prev-position tap
            float Xt = fmaf(K,  dl, XP);    // true last-tap value
            float t0 = fmaf(-A,  Si, uP0);
            float t1 = fmaf(A2,  Si, uP1);
            float t2 = fmaf(mA3, Si, uP2);
            float t3 = fmaf(A4,  Si, uP3);

            // ---- filler 3: SX-work for sample k+1 ----
            float pE4 = rshr<0x112>(Xt);
            float c0 = fmaf(A, t0, pos0 ? dl : pE4);
            float c1 = fmaf(A, t1, t0);
            float c2 = fmaf(A, t2, t1);
            float c3 = fmaf(A, t3, t2);
            float c4 = fmaf(A, Xt, t3);
            float u0 = c0;
            float u1 = fmaf(-A, u0, c1);
            float u2 = fmaf(-A, u1, c2);
            float u3 = fmaf(-A, u2, c3);
            float u4 = fmaf(-A, u3, c4);
            float Xn = u4;
            Xn = fmaf(rshr<0x112>(Xn), Rv,  Xn);
            Xn = fmaf(rshr<0x114>(Xn), R2v, Xn);
            float XSn = rshr<0x112>(Xn);               // bound_ctrl -> 0 @pos0
            float fpX = u0 * B0;
            fpX = fmaf(u1, B1, fpX);
            fpX = fmaf(u2, B2, fpX);
            fpX = fmaf(u3, B3, fpX);
            fpX = fmaf(Xn, B4, fpX);
            fpX = fmaf(XSn, GB, fpX);
            float SXn = fpX;
            SXn += rshr<0x112>(SXn);
            SXn += rshr<0x114>(SXn);
            SXn += rshr<0x118>(SXn);

            // ---- glue: consume the cross-lane results (latency hidden) ----
#if HAVE_PLSWAP
            float S2 = __uint_as_float(rr.x) + __uint_as_float(rr.y);
            float aE = rlane(S2, 14), bE = rlane(S2, 30);
            float aO = rlane(S2, 15), bO = rlane(S2, 31);
            float tot = parodd ? (aO + bO) : (aE + bE);
            float x2 = y1 + tot;
            float dif = parodd ? (aO - bO) : (aE - bE);
            yb[k8 + j] = x2 + dif;
#else
            float s0p = rlane(S, 14), s1p = rlane(S, 30);
            float s2p = rlane(S, 46), s3p = rlane(S, 62);
            float s0a = rlane(S, 15), s1a = rlane(S, 31);
            float s2a = rlane(S, 47), s3a = rlane(S, 63);
            float eP = s0p + s2p, oP = s1p + s3p;
            float eA = s0a + s2a, oA = s1a + s3a;
            float ce = parodd ? eA : eP;
            float co = parodd ? oA : oP;
            float x2 = y1 + (ce + co);
            yb[k8 + j] = x2 + (ce - co);
#endif
            float xprev = (parodd ? TT1 : TT0) * IPwv;
            xin = row0 ? x2 : xprev;

            // ---- rotate pipeline ----
            uP0 = u0; uP1 = u1; uP2 = u2; uP3 = u3;
            XP = Xn; XSP = XSn; SXP = SXn;
            dlp = dl;
        }
    }
}

// ---------------------------------------------------------------------------
// Kernel D: MLSA synthesis scan. block = ONE wave = one (96-sample output
// window, batch); P/A on even/odd lanes; P+A combine in LDS -> plain stores.
// ---------------------------------------------------------------------------
__global__ __launch_bounds__(64) void mlsa_kernel(
    const float* __restrict__ bcoef, const float* __restrict__ exc,
    float* __restrict__ out)
{
    // row stride 124 floats = 496 B: 16B-aligned AND parity rows 28 banks
    // apart (r5's +8 pad put them in the SAME bank -> 1.47M conflicts)
    __shared__ __align__(16) float sexc[2][HOPW + 4];
    __shared__ __align__(16) float ybuf[2][HOPW + 4];

    const int tid = threadIdx.x;
    const int par = tid & 1;              // 0 = periodic, 1 = aperiodic
    const int pos = (tid >> 1) & 7;       // order-position within row
    const int row = tid >> 4;             // Pade tap row
    const int slot = blockIdx.x >> 2;     // 0..249: output window index
    const int b = blockIdx.x & 3;
    const int f = par * 4 + b;
    const bool pos0 = (pos == 0), row0 = (row == 0), parodd = (par != 0);

    const float P1 = 0.4999273f, P2 = 0.1067005f, P3 = 0.00956526f, P4 = 0.0003041358f;
    const float wrow = (row == 0) ? P1 : (row == 1) ? -P2 : (row == 2) ? P3 : -P4;
    const float IPw  = (row == 1) ? (1.f / P1) : (row == 2) ? (-1.f / P2)
                     : (row == 3) ? (1.f / P3) : 0.f;

    const float A = ALPHA;
    const float A2c = A * A;
    const float mA3c = -(A * A2c);
    const float A4c = A2c * A2c;
    const float R = -(A4c * A);
    float KS = 1.f;                       // R^pos
    for (int j = 0; j < pos; ++j) KS *= R;
    const float K = KS * R;               // R^(pos+1)

    // pipeline + filter state
    float uP0 = 0.f, uP1 = 0.f, uP2 = 0.f, uP3 = 0.f;
    float XP = 0.f, XSP = 0.f, SXP = 0.f;
    float dlp = 0.f, xin = 0.f;
    float m1 = 0.f, m2 = 0.f, m3 = 0.f, m4 = 0.f, w0 = 0.f;

    const float* sxp = sexc[par];
    float* ybp = ybuf[par];
    const int ja = 5 * pos + 2;
    const int lh = tid >> 1;

    const int o0 = slot * OUTS;           // first output sample
    const int s0 = o0 - WARMS;            // first warm sample (may be < 0)
    const int fA = (s0 <= 0) ? 0 : (s0 / HOPW);
    const int fB = (o0 + OUTS - 1) / HOPW;

    #pragma unroll 1
    for (int ft = fA; ft <= fB; ++ft) {
        const float* bp = bcoef + (f * T_FRAMES + ft) * M1;
        const float b1 = bp[1];
        const float G  = expf(bp[0]);
        const float AAc = 1.0f - A * A;
        const float AB = AAc * b1;
        const float BP1 = b1 * P1, BP2 = b1 * P2, BP3 = b1 * P3, BP4 = b1 * P4;

        // stage own-parity excitation, pre-scaled by this filter's gain
        const float* ex = exc + f * NSAMP + ft * HOPW;
        #pragma unroll
        for (int m = 0; m < 4; ++m) {
            int kk = lh + 32 * m;
            if (kk < HOPW) sexc[par][kk] = ex[kk] * G;
        }

        // orders ja..ja+4; valid order <= 39 (pos=7 covers 37..39 only)
        const float B0c = bp[ja]     * wrow;
        const float B1c = bp[ja + 1] * wrow;
        const float B2c = bp[ja + 2] * wrow;
        const float B3c = (pos < 7) ? bp[ja + 3] * wrow : 0.f;
        const float B4c = (pos < 7) ? bp[ja + 4] * wrow : 0.f;

        // per-frame constants: GB, CKp = prefix(KS*GB + K*B4)
        const float GBc = fmaf(A4c, B3c, fmaf(mA3c, B2c, fmaf(A2c, B1c, -A * B0c)));
        const float fpK = fmaf(K, B4c, KS * GBc);
        float CKp = fpK;
        CKp += rshr<0x112>(CKp);
        CKp += rshr<0x114>(CKp);
        CKp += rshr<0x118>(CKp);

        // refresh SXP for this frame's first sample (u/X/XS are B-free and
        // carry across frames; only the B-weighted dot+prefix changes)
        float fpX0 = uP0 * B0c;
        fpX0 = fmaf(uP1, B1c, fpX0);
        fpX0 = fmaf(uP2, B2c, fpX0);
        fpX0 = fmaf(uP3, B3c, fpX0);
        fpX0 = fmaf(XP,  B4c, fpX0);
        fpX0 = fmaf(XSP, GBc, fpX0);
        SXP = fpX0;
        SXP += rshr<0x112>(SXP);
        SXP += rshr<0x114>(SXP);
        SXP += rshr<0x118>(SXP);

        // runtime sample window of this frame (all bounds multiples of 8)
        int ks = s0 - ft * HOPW; if (ks < 0) ks = 0;
        int ke = o0 + OUTS - ft * HOPW; if (ke > HOPW) ke = HOPW;

        run_frame(sxp, AB, BP1, BP2, BP3, BP4,
                  B0c, B1c, B2c, B3c, B4c, GBc, CKp, K, KS, IPw,
                  pos0, row0, parodd,
                  uP0, uP1, uP2, uP3, XP, XSP, SXP,
                  dlp, xin, m1, m2, m3, m4, w0,
                  ybp, ks, ke);

        // store this frame's output window [kout, ke), P+A combined in LDS
        int kout = o0 - ft * HOPW; if (kout < 0) kout = 0;
        if (kout < ke) {
            float* op = out + b * NSAMP + ft * HOPW;
            int i0 = kout + tid;
            if (i0 < ke) op[i0] = ybuf[0][i0] + ybuf[1][i0];
            int i1 = i0 + 64;
            if (i1 < ke) op[i1] = ybuf[0][i1] + ybuf[1][i1];
        }
    }
}

// ---------------------------------------------------------------------------
extern "C" void kernel_launch(void* const* d_in, const int* in_sizes, int n_in,
                              void* d_out, int out_size, void* d_ws, size_t ws_size,
                              hipStream_t stream) {
    const float* mceps = (const float*)d_in[0];
    const float* apdcs = (const float*)d_in[1];
    const float* f0s   = (const float*)d_in[2];
    const float* noise = (const float*)d_in[3];
    const float* Wm  = (const float*)d_in[4];
    const float* bm  = (const float*)d_in[5];
    const float* Wa  = (const float*)d_in[6];
    const float* ba  = (const float*)d_in[7];
    const float* Wf  = (const float*)d_in[8];
    const float* bf  = (const float*)d_in[9];
    const float* Wpa = (const float*)d_in[10];
    const float* bpa = (const float*)d_in[11];
    const float* Wpp = (const float*)d_in[12];
    const float* bpp = (const float*)d_in[13];
    const float* Wrp = (const float*)d_in[14];
    const float* brp = (const float*)d_in[15];
    const float* Wra = (const float*)d_in[16];
    const float* bra = (const float*)d_in[17];
    const float* Wap = (const float*)d_in[18];
    float* out = (float*)d_out;

    char* ws = (char*)d_ws;
    float* bcoef = (float*)(ws + 0);           // 256000 B
    float* exc   = (float*)(ws + 256000);      // 768000 B

    prep_kernel<<<dim3(EMB_BLOCKS + 8 * BPF), dim3(256), 0, stream>>>(
        mceps, apdcs, f0s, noise, Wm, bm, Wa, ba, Wf, bf,
        Wpa, bpa, Wpp, bpp, Wrp, brp, Wra, bra, Wap, bcoef, exc);

    // every output sample owned by exactly one block -> no memset, no atomics
    mlsa_kernel<<<dim3(SLOTS * 4), dim3(64), 0, stream>>>(bcoef, exc, out);
}

// Round 7
// 190.163 us; speedup vs baseline: 1.0513x; 1.0513x over previous
//
#include <hip/hip_runtime.h>
#include <math.h>

#define ALPHA 0.466f
#define T_FRAMES 200
#define HOPW 120
#define NSAMP 24000
#define M1 40
#define HID 256
#define CONDW 192

// Chunked MLSA scan: each wave owns one (batch, 96-sample output window),
// 384 warm samples from zero state (transient < 0.03125 noise floor, r2).
// ONE WAVE PER BLOCK; 1000 blocks <= 1024 SIMDs. P/A filters on even/odd
// lanes. r3-r6 lessons: per-sample time ~= cross-lane-op count x ~17-20cyc
// (wave-blocking, dependency-shape-independent); plain-VALU diet and
// dependency restructures are worthless. This round: remove one cross-lane
// op (X-hop2, weight (-A)^10 ~ 4.8e-4) and prefetch next-frame coefs +
// excitation during the current frame's sample loop (hides the ~500-900cyc
// inter-frame global->LDS stall).
#define WARMS 384
#define OUTS 96
#define SLOTS (NSAMP / OUTS)     // 250 per batch -> 1000 blocks

#define F8 8
#define EMB_BLOCKS (4 * T_FRAMES / F8)       // 100
#define BPF ((NSAMP + 255) / 256)            // 94

#if defined(__has_builtin)
#  if __has_builtin(__builtin_amdgcn_permlane32_swap)
#    define HAVE_PLSWAP 1
#  endif
#endif
#ifndef HAVE_PLSWAP
#  define HAVE_PLSWAP 0
#endif

// ---------------------------------------------------------------------------
// Kernel P: embed (blocks 0..99) U exc (blocks 100..851) in ONE dispatch.
// (unchanged)
// ---------------------------------------------------------------------------
__global__ __launch_bounds__(256) void prep_kernel(
    const float* __restrict__ mceps, const float* __restrict__ apdcs,
    const float* __restrict__ f0s, const float* __restrict__ noise,
    const float* __restrict__ Wm, const float* __restrict__ bm,
    const float* __restrict__ Wa, const float* __restrict__ ba,
    const float* __restrict__ Wf, const float* __restrict__ bf,
    const float* __restrict__ Wpa, const float* __restrict__ bpa,
    const float* __restrict__ Wpp, const float* __restrict__ bpp,
    const float* __restrict__ Wrp, const float* __restrict__ brp,
    const float* __restrict__ Wra, const float* __restrict__ bra,
    const float* __restrict__ Wap,
    float* __restrict__ bcoef, float* __restrict__ exc)
{
    const int tid = threadIdx.x;

    if (blockIdx.x >= EMB_BLOCKS) {
        const int xb = blockIdx.x - EMB_BLOCKS;
        const int ff = xb / BPF;
        const int n = (xb % BPF) * 256 + tid;

        if (ff >= 4) {
            if (n < NSAMP) exc[ff * NSAMP + n] = 0.5f * noise[(ff - 4) * NSAMP + n];
            return;
        }

        __shared__ double s_base[T_FRAMES];
        __shared__ double s_step[T_FRAMES];
        __shared__ float  s_amp[T_FRAMES];

        if (tid < 64) {
            const int L = tid;
            double st[4], loc[4];
            float am[4];
            double s = 0.0;
            #pragma unroll
            for (int j = 0; j < 4; ++j) {
                int ft = L * 4 + j;
                if (ft < T_FRAMES) {
                    double fv = exp((double)f0s[ff * T_FRAMES + ft] * 0.25 + 5.0);
                    st[j] = fv / 24000.0;
                    am[j] = (float)(0.5 * sqrt(24000.0 / fmax(fv, 1.0)));
                } else { st[j] = 0.0; am[j] = 0.f; }
                loc[j] = s;
                s += st[j];
            }
            double tot = s;
            #pragma unroll
            for (int off = 1; off < 64; off <<= 1) {
                double v = __shfl_up(s, off, 64);
                if (L >= off) s += v;
            }
            double excl = s - tot;
            #pragma unroll
            for (int j = 0; j < 4; ++j) {
                int ft = L * 4 + j;
                if (ft < T_FRAMES) {
                    s_base[ft] = 120.0 * (excl + loc[j]);
                    s_step[ft] = st[j];
                    s_amp[ft]  = am[j];
                }
            }
        }
        __syncthreads();

        if (n < NSAMP) {
            int ft = n / HOPW, k = n - ft * HOPW;
            double st = s_step[ft], bs = s_base[ft];
            double ph  = bs + (double)(k + 1) * st;
            double php = bs + (double)k * st;
            exc[ff * NSAMP + n] = (floor(ph) > floor(php)) ? s_amp[ft] : 0.0f;
        }
        return;
    }

    // =================== embed path (blocks 0..99) ===================
    __shared__ float s_mc[F8][M1];
    __shared__ float s_ap[F8][5];
    __shared__ float s_f0[F8];
    __shared__ float s_h[F8][HID];
    __shared__ float s_ca[F8][CONDW];
    __shared__ float s_cp[F8][CONDW];
    __shared__ float s_mcp[F8][M1];
    __shared__ float s_mca[F8][M1];

    const int R0 = blockIdx.x * F8;

    for (int j = tid; j < F8 * M1; j += 256) s_mc[j / M1][j % M1] = mceps[R0 * M1 + j];
    if (tid < F8 * 5) s_ap[tid / 5][tid % 5] = apdcs[R0 * 5 + tid];
    if (tid < F8)     s_f0[tid] = f0s[R0 + tid];
    __syncthreads();

    {
        float acc[F8];
        const float bias = bm[tid] + ba[tid] + bf[tid];
        #pragma unroll
        for (int r = 0; r < F8; ++r) acc[r] = bias;
        for (int k = 0; k < M1; ++k) {
            float w = Wm[k * HID + tid];
            #pragma unroll
            for (int r = 0; r < F8; ++r) acc[r] = fmaf(s_mc[r][k], w, acc[r]);
        }
        #pragma unroll
        for (int k = 0; k < 5; ++k) {
            float w = Wa[k * HID + tid];
            #pragma unroll
            for (int r = 0; r < F8; ++r) acc[r] = fmaf(s_ap[r][k], w, acc[r]);
        }
        float wf = Wf[tid];
        #pragma unroll
        for (int r = 0; r < F8; ++r) s_h[r][tid] = fmaf(s_f0[r], wf, acc[r]);
    }
    __syncthreads();

    if (tid < CONDW) {
        float aA[F8], aP[F8];
        #pragma unroll
        for (int r = 0; r < F8; ++r) { aA[r] = bpa[tid]; aP[r] = bpp[tid]; }
        for (int k = 0; k < HID; k += 4) {
            float4 h4[F8];
            #pragma unroll
            for (int r = 0; r < F8; ++r) h4[r] = *(const float4*)&s_h[r][k];
            #pragma unroll
            for (int kk = 0; kk < 4; ++kk) {
                float wa = Wpa[(k + kk) * CONDW + tid];
                float wp = Wpp[(k + kk) * CONDW + tid];
                #pragma unroll
                for (int r = 0; r < F8; ++r) {
                    float hv = (&h4[r].x)[kk];
                    aA[r] = fmaf(hv, wa, aA[r]);
                    aP[r] = fmaf(hv, wp, aP[r]);
                }
            }
        }
        #pragma unroll
        for (int r = 0; r < F8; ++r) { s_ca[r][tid] = aA[r]; s_cp[r][tid] = aP[r]; }
    }
    __syncthreads();

    if (tid < M1) {
        const int u = tid;
        float acc[F8];
        #pragma unroll
        for (int r = 0; r < F8; ++r) acc[r] = brp[u];
        for (int k = 0; k < CONDW; k += 4) {
            float4 c4[F8];
            #pragma unroll
            for (int r = 0; r < F8; ++r) c4[r] = *(const float4*)&s_cp[r][k];
            #pragma unroll
            for (int kk = 0; kk < 4; ++kk) {
                float w = Wrp[(k + kk) * M1 + u];
                #pragma unroll
                for (int r = 0; r < F8; ++r) acc[r] = fmaf((&c4[r].x)[kk], w, acc[r]);
            }
        }
        #pragma unroll
        for (int r = 0; r < F8; ++r)
            s_mcp[r][u] = s_mc[r][u] + 0.1f * tanhf(acc[r]);
    } else if (tid >= 64 && tid < 64 + M1) {
        const int u = tid - 64;
        float acc[F8];
        #pragma unroll
        for (int r = 0; r < F8; ++r) acc[r] = bra[u];
        for (int k = 0; k < CONDW; k += 4) {
            float4 c4[F8];
            #pragma unroll
            for (int r = 0; r < F8; ++r) c4[r] = *(const float4*)&s_ca[r][k];
            #pragma unroll
            for (int kk = 0; kk < 4; ++kk) {
                float w = Wra[(k + kk) * M1 + u];
                #pragma unroll
                for (int r = 0; r < F8; ++r) acc[r] = fmaf((&c4[r].x)[kk], w, acc[r]);
            }
        }
        #pragma unroll
        for (int r = 0; r < F8; ++r) {
            float aw = 0.f;
            #pragma unroll
            for (int j = 0; j < 5; ++j) aw = fmaf(s_ap[r][j], Wap[j * M1 + u], aw);
            s_mca[r][u] = s_mc[r][u] + 0.1f * tanhf(acc[r]) + aw;
        }
    }
    __syncthreads();

    if (tid < 16) {
        const int r = tid >> 1, path = tid & 1;
        const int R = R0 + r;
        const int batch = R / T_FRAMES, t = R - batch * T_FRAMES;
        const float* src = path ? s_mca[r] : s_mcp[r];
        float* dst = bcoef + ((path * 4 + batch) * T_FRAMES + t) * M1;
        float prev = src[M1 - 1];
        dst[M1 - 1] = prev;
        for (int m = M1 - 2; m >= 0; --m) {
            prev = src[m] - ALPHA * prev;
            dst[m] = prev;
        }
    }
}

// ---------------------------------------------------------------------------
// DPP helpers. row_shr:N = 0x110|N; row_bcast15 = 0x142.
// ---------------------------------------------------------------------------
template <int CTRL>
__device__ __forceinline__ float rshr(float x) {
    return __int_as_float(
        __builtin_amdgcn_mov_dpp(__float_as_int(x), CTRL, 0xF, 0xF, true));
}
__device__ __forceinline__ float rlane(float x, int l) {
    return __int_as_float(__builtin_amdgcn_readlane(__float_as_int(x), l));
}
// pin a wave-uniform value into a VGPR (DPP-fusable VOP2 forms need vsrc1=VGPR)
__device__ __forceinline__ float vpin(float x) {
    asm("" : "+v"(x));
    return x;
}

// ---------------------------------------------------------------------------
// Samples [ks, ke) of one frame of the lane-parallel dual-filter MLSA scan:
// P on even lanes, A on odd lanes; 8 order-positions x 5 taps per lane;
// Pade rows = tid>>4. r7: X-chain hop2 ((-A)^10 ~ 4.8e-4, steady-state
// output bias ~0.004 << 0.28 threshold) dropped in addition to hop3 (r3) --
// removes one cross-lane op from the per-sample cost. y2 = fma(2,a,y1)
// (exact algebra; carried x2 rounding order unchanged).
// ---------------------------------------------------------------------------
__device__ __forceinline__ void run_frame(
    const float* __restrict__ sx, float AB,
    float BP1, float BP2, float BP3, float BP4,
    float B0, float B1, float B2, float B3, float B4,
    float K, float IPw, bool pos0, bool row0, bool parodd,
    float& E0, float& E1, float& E2, float& E3, float& E4,
    float& dlp, float& xin,
    float& m1, float& m2, float& m3, float& m4, float& w0,
    float* __restrict__ yb, int ks, int ke)
{
    const float A   = ALPHA;
    const float AA  = 1.0f - A * A;
    const float A2  = A * A;
    const float mA3 = -(A * A2);
    const float A4  = A2 * A2;
    const float R   = -(A4 * A);     // (-A)^5 : inter-position ratio

    const float Rv   = vpin(R);
    const float IPwv = vpin(IPw);

    #pragma unroll 1
    for (int k8 = ks; k8 < ke; k8 += 8) {
        const float4 g0 = *(const float4*)&sx[k8];
        const float4 g1 = *(const float4*)&sx[k8 + 4];
        const float xs[8] = {g0.x, g0.y, g0.z, g0.w, g1.x, g1.y, g1.z, g1.w};
        #pragma unroll
        for (int j = 0; j < 8; ++j) {
            float x = xs[j];                           // G pre-folded

            // stage 1 (SPTK mlsadf1), b1-rescaled; y1 = x + 2p
            float na0 = fmaf(A, m1, AA * w0);
            float na1 = fmaf(A, m2, AB * m1);
            float na2 = fmaf(A, m3, AB * m2);
            float na3 = fmaf(A, m4, AB * m3);
            float p = fmaf(na2, BP3, na0 * BP1);
            float q = fmaf(na3, BP4, na1 * BP2);
            float x1 = x + (p - q);
            float y1 = fmaf(2.0f, p, x);
            m1 = na0; m2 = na1; m3 = na2; m4 = na3; w0 = x1;

            // stage 2: 5-tap blocked affine scan over 8 positions (stride 2)
            float pE4 = rshr<0x112>(E4);
            float c0 = fmaf(A, E0, pos0 ? dlp : pE4);
            float c1 = fmaf(A, E1, E0);
            float c2 = fmaf(A, E2, E1);
            float c3 = fmaf(A, E3, E2);
            float c4 = fmaf(A, E4, E3);
            float u0 = c0;
            float u1 = fmaf(-A, u0, c1);
            float u2 = fmaf(-A, u1, c2);
            float u3 = fmaf(-A, u2, c3);
            float u4 = fmaf(-A, u3, c4);
            float X = u4;
            X = fmaf(rshr<0x112>(X), Rv, X);
            // hop2 ((-A)^10) and hop3 ((-A)^20) dropped: << noise floor
            float dl = fmaf(AA, xin, A * dlp);
            float Xt = fmaf(K, dl, X);                 // true last-tap value
            float Si = rshr<0x112>(Xt);
            Si = pos0 ? dl : Si;                       // true prev-position tap
            float t0 = fmaf(-A,  Si, u0);
            float t1 = fmaf(A2,  Si, u1);
            float t2 = fmaf(mA3, Si, u2);
            float t3 = fmaf(A4,  Si, u3);

            // signed P-weighted fy partial + row prefix -> row totals = +-v2_r
            float fp = t0 * B0;
            fp = fmaf(t1, B1, fp);
            fp = fmaf(t2, B2, fp);
            fp = fmaf(t3, B3, fp);
            fp = fmaf(Xt, B4, fp);
            float S = fp;
            S += rshr<0x112>(S);
            S += rshr<0x114>(S);
            S += rshr<0x118>(S);

            // prev-row same-parity total for rows 1-3
            float Sx  = rshr<0x111>(S);
            float T1m = rshr<0x142>(S)  * IPwv;
            float T0m = rshr<0x142>(Sx) * IPwv;
            float xprev = parodd ? T1m : T0m;

            // glue: per-parity signed 4-row totals; y2 = y1 + 2a (exact)
#if HAVE_PLSWAP
            typedef unsigned u32x2 __attribute__((ext_vector_type(2)));
            u32x2 rr = __builtin_amdgcn_permlane32_swap(
                __float_as_uint(S), __float_as_uint(S), false, false);
            float S2 = __uint_as_float(rr.x) + __uint_as_float(rr.y);
            float aE = rlane(S2, 14), bE = rlane(S2, 30);
            float aO = rlane(S2, 15), bO = rlane(S2, 31);
            float a  = parodd ? aO : aE;
            float bb = parodd ? bO : bE;
            float x2 = y1 + (a + bb);
            yb[k8 + j] = fmaf(2.0f, a, y1);
#else
            float s0p = rlane(S, 14), s1p = rlane(S, 30);
            float s2p = rlane(S, 46), s3p = rlane(S, 62);
            float s0a = rlane(S, 15), s1a = rlane(S, 31);
            float s2a = rlane(S, 47), s3a = rlane(S, 63);
            float eP = s0p + s2p, oP = s1p + s3p;
            float eA = s0a + s2a, oA = s1a + s3a;
            float ce = parodd ? eA : eP;
            float co = parodd ? oA : oP;
            float x2 = y1 + (ce + co);
            yb[k8 + j] = fmaf(2.0f, ce, y1);
#endif

            // next-sample inputs
            xin = row0 ? x2 : xprev;
            E0 = t0; E1 = t1; E2 = t2; E3 = t3; E4 = Xt;
            dlp = dl;
        }
    }
}

// ---------------------------------------------------------------------------
// Kernel D: MLSA synthesis scan. block = ONE wave = one (96-sample output
// window, batch); P/A on even/odd lanes; P+A combine in LDS -> plain stores.
// Next-frame bcoef + excitation are PREFETCHED into registers during the
// current frame's sample loop (double-buffered sexc) so the inter-frame
// global->LDS->ds_read stall (~500-900cyc) hides under ~40K cyc of compute.
// ---------------------------------------------------------------------------
__global__ __launch_bounds__(64) void mlsa_kernel(
    const float* __restrict__ bcoef, const float* __restrict__ exc,
    float* __restrict__ out)
{
    // row stride 124 floats = 496 B: 16B-aligned, parity rows 28 banks apart
    __shared__ __align__(16) float sexc[2][2][HOPW + 4];   // [buf][par][..]
    __shared__ __align__(16) float ybuf[2][HOPW + 4];

    const int tid = threadIdx.x;
    const int par = tid & 1;              // 0 = periodic, 1 = aperiodic
    const int pos = (tid >> 1) & 7;       // order-position within row
    const int row = tid >> 4;             // Pade tap row
    const int slot = blockIdx.x >> 2;     // 0..249: output window index
    const int b = blockIdx.x & 3;
    const int f = par * 4 + b;
    const bool pos0 = (pos == 0), row0 = (row == 0), parodd = (par != 0);

    const float P1 = 0.4999273f, P2 = 0.1067005f, P3 = 0.00956526f, P4 = 0.0003041358f;
    const float wrow = (row == 0) ? P1 : (row == 1) ? -P2 : (row == 2) ? P3 : -P4;
    const float IPw  = (row == 1) ? (1.f / P1) : (row == 2) ? (-1.f / P2)
                     : (row == 3) ? (1.f / P3) : 0.f;

    const float A = ALPHA;
    const float AAc = 1.0f - A * A;
    const float R = -(A * A * A * A * A);
    float K = R;
    for (int j = 0; j < pos; ++j) K *= R;

    float E0 = 0.f, E1 = 0.f, E2 = 0.f, E3 = 0.f, E4 = 0.f;
    float dlp = 0.f, xin = 0.f;
    float m1 = 0.f, m2 = 0.f, m3 = 0.f, m4 = 0.f, w0 = 0.f;

    float* ybp = ybuf[par];
    const int ja = 5 * pos + 2;
    const int lh = tid >> 1;              // 0..31

    const int o0 = slot * OUTS;           // first output sample
    const int s0 = o0 - WARMS;            // first warm sample (may be < 0)
    const int fA = (s0 <= 0) ? 0 : (s0 / HOPW);
    const int fB = (o0 + OUTS - 1) / HOPW;

    // ---- prologue: load + stage frame fA, compute its constants ----
    {
        const float* bp0 = bcoef + (f * T_FRAMES + fA) * M1;
        const float* ex0 = exc + f * NSAMP + fA * HOPW;
        float G0 = expf(bp0[0]);
        sexc[0][par][lh]      = ex0[lh]      * G0;
        sexc[0][par][lh + 32] = ex0[lh + 32] * G0;
        sexc[0][par][lh + 64] = ex0[lh + 64] * G0;
        if (lh < HOPW - 96) sexc[0][par][lh + 96] = ex0[lh + 96] * G0;
    }
    const float* bpA = bcoef + (f * T_FRAMES + fA) * M1;
    float b1c = bpA[1];
    float AB  = AAc * b1c;
    float BP1 = b1c * P1, BP2 = b1c * P2, BP3 = b1c * P3, BP4 = b1c * P4;
    float B0c = bpA[ja]     * wrow;
    float B1c = bpA[ja + 1] * wrow;
    float B2c = bpA[ja + 2] * wrow;
    float B3c = (pos < 7) ? bpA[ja + 3] * wrow : 0.f;
    float B4c = (pos < 7) ? bpA[ja + 4] * wrow : 0.f;

    int bufi = 0;

    #pragma unroll 1
    for (int ft = fA; ft <= fB; ++ft) {
        const bool hasnext = (ft < fB);
        const int ftn = hasnext ? ft + 1 : ft;      // safe dummy addr if last

        // ---- issue next-frame loads NOW (latency hides under run_frame) ----
        const float* bpn = bcoef + (f * T_FRAMES + ftn) * M1;
        const float* exn = exc + f * NSAMP + ftn * HOPW;
        float n_b0 = bpn[0];
        float n_b1 = bpn[1];
        float n_j0 = bpn[ja], n_j1 = bpn[ja + 1], n_j2 = bpn[ja + 2];
        float n_j3 = (pos < 7) ? bpn[ja + 3] : 0.f;
        float n_j4 = (pos < 7) ? bpn[ja + 4] : 0.f;
        float ne0 = exn[lh];
        float ne1 = exn[lh + 32];
        float ne2 = exn[lh + 64];
        float ne3 = (lh < HOPW - 96) ? exn[lh + 96] : 0.f;

        // runtime sample window of this frame (all bounds multiples of 8)
        int ks = s0 - ft * HOPW; if (ks < 0) ks = 0;
        int ke = o0 + OUTS - ft * HOPW; if (ke > HOPW) ke = HOPW;

        run_frame(sexc[bufi][par], AB, BP1, BP2, BP3, BP4,
                  B0c, B1c, B2c, B3c, B4c, K, IPw, pos0, row0, parodd,
                  E0, E1, E2, E3, E4, dlp, xin, m1, m2, m3, m4, w0,
                  ybp, ks, ke);

        // store this frame's output window [kout, ke), P+A combined in LDS
        int kout = o0 - ft * HOPW; if (kout < 0) kout = 0;
        if (kout < ke) {
            float* op = out + b * NSAMP + ft * HOPW;
            int i0 = kout + tid;
            if (i0 < ke) op[i0] = ybuf[0][i0] + ybuf[1][i0];
            int i1 = i0 + 64;
            if (i1 < ke) op[i1] = ybuf[0][i1] + ybuf[1][i1];
        }

        // ---- commit prefetched frame: stage + swap constants ----
        if (hasnext) {
            const int nb = bufi ^ 1;
            float Gn = expf(n_b0);
            sexc[nb][par][lh]      = ne0 * Gn;
            sexc[nb][par][lh + 32] = ne1 * Gn;
            sexc[nb][par][lh + 64] = ne2 * Gn;
            if (lh < HOPW - 96) sexc[nb][par][lh + 96] = ne3 * Gn;
            AB  = AAc * n_b1;
            BP1 = n_b1 * P1; BP2 = n_b1 * P2; BP3 = n_b1 * P3; BP4 = n_b1 * P4;
            B0c = n_j0 * wrow;
            B1c = n_j1 * wrow;
            B2c = n_j2 * wrow;
            B3c = n_j3 * wrow;
            B4c = n_j4 * wrow;
            bufi = nb;
        }
    }
}

// ---------------------------------------------------------------------------
extern "C" void kernel_launch(void* const* d_in, const int* in_sizes, int n_in,
                              void* d_out, int out_size, void* d_ws, size_t ws_size,
                              hipStream_t stream) {
    const float* mceps = (const float*)d_in[0];
    const float* apdcs = (const float*)d_in[1];
    const float* f0s   = (const float*)d_in[2];
    const float* noise = (const float*)d_in[3];
    const float* Wm  = (const float*)d_in[4];
    const float* bm  = (const float*)d_in[5];
    const float* Wa  = (const float*)d_in[6];
    const float* ba  = (const float*)d_in[7];
    const float* Wf  = (const float*)d_in[8];
    const float* bf  = (const float*)d_in[9];
    const float* Wpa = (const float*)d_in[10];
    const float* bpa = (const float*)d_in[11];
    const float* Wpp = (const float*)d_in[12];
    const float* bpp = (const float*)d_in[13];
    const float* Wrp = (const float*)d_in[14];
    const float* brp = (const float*)d_in[15];
    const float* Wra = (const float*)d_in[16];
    const float* bra = (const float*)d_in[17];
    const float* Wap = (const float*)d_in[18];
    float* out = (float*)d_out;

    char* ws = (char*)d_ws;
    float* bcoef = (float*)(ws + 0);           // 256000 B
    float* exc   = (float*)(ws + 256000);      // 768000 B

    prep_kernel<<<dim3(EMB_BLOCKS + 8 * BPF), dim3(256), 0, stream>>>(
        mceps, apdcs, f0s, noise, Wm, bm, Wa, ba, Wf, bf,
        Wpa, bpa, Wpp, bpp, Wrp, brp, Wra, bra, Wap, bcoef, exc);

    // every output sample owned by exactly one block -> no memset, no atomics
    mlsa_kernel<<<dim3(SLOTS * 4), dim3(64), 0, stream>>>(bcoef, exc, out);
}

// Round 8
// 188.597 us; speedup vs baseline: 1.0601x; 1.0083x over previous
//
#include <hip/hip_runtime.h>
#include <math.h>

#define ALPHA 0.466f
#define T_FRAMES 200
#define HOPW 120
#define NSAMP 24000
#define M1 40
#define HID 256
#define CONDW 192

// Chunked MLSA scan: each wave owns one (batch, 96-sample output window),
// 384 warm samples from zero state. ONE WAVE PER BLOCK; 1000 blocks <= 1024
// SIMDs. P/A filters on even/odd lanes. Model (r3-r7, confirmed r7):
// per-sample cost ~= cross-lane ops x ~17-20cyc + ~90cyc base; plain VALU
// ~free. r8: (a) Si/pE4 dedup -- shr2(E4) == shr2(Xt_{k-1}) == SiR carried
// from the previous sample, deletes 1 DPP/sample bit-exactly; (b) software-
// pipelined excitation ds_reads (issue group k8+8 before consuming k8);
// (c) yb writes batched 8->2 ds_write_b128 per group.
#define WARMS 384
#define OUTS 96
#define SLOTS (NSAMP / OUTS)     // 250 per batch -> 1000 blocks

#define F8 8
#define EMB_BLOCKS (4 * T_FRAMES / F8)       // 100
#define BPF ((NSAMP + 255) / 256)            // 94

#if defined(__has_builtin)
#  if __has_builtin(__builtin_amdgcn_permlane32_swap)
#    define HAVE_PLSWAP 1
#  endif
#endif
#ifndef HAVE_PLSWAP
#  define HAVE_PLSWAP 0
#endif

// ---------------------------------------------------------------------------
// Kernel P: embed (blocks 0..99) U exc (blocks 100..851) in ONE dispatch.
// (unchanged)
// ---------------------------------------------------------------------------
__global__ __launch_bounds__(256) void prep_kernel(
    const float* __restrict__ mceps, const float* __restrict__ apdcs,
    const float* __restrict__ f0s, const float* __restrict__ noise,
    const float* __restrict__ Wm, const float* __restrict__ bm,
    const float* __restrict__ Wa, const float* __restrict__ ba,
    const float* __restrict__ Wf, const float* __restrict__ bf,
    const float* __restrict__ Wpa, const float* __restrict__ bpa,
    const float* __restrict__ Wpp, const float* __restrict__ bpp,
    const float* __restrict__ Wrp, const float* __restrict__ brp,
    const float* __restrict__ Wra, const float* __restrict__ bra,
    const float* __restrict__ Wap,
    float* __restrict__ bcoef, float* __restrict__ exc)
{
    const int tid = threadIdx.x;

    if (blockIdx.x >= EMB_BLOCKS) {
        const int xb = blockIdx.x - EMB_BLOCKS;
        const int ff = xb / BPF;
        const int n = (xb % BPF) * 256 + tid;

        if (ff >= 4) {
            if (n < NSAMP) exc[ff * NSAMP + n] = 0.5f * noise[(ff - 4) * NSAMP + n];
            return;
        }

        __shared__ double s_base[T_FRAMES];
        __shared__ double s_step[T_FRAMES];
        __shared__ float  s_amp[T_FRAMES];

        if (tid < 64) {
            const int L = tid;
            double st[4], loc[4];
            float am[4];
            double s = 0.0;
            #pragma unroll
            for (int j = 0; j < 4; ++j) {
                int ft = L * 4 + j;
                if (ft < T_FRAMES) {
                    double fv = exp((double)f0s[ff * T_FRAMES + ft] * 0.25 + 5.0);
                    st[j] = fv / 24000.0;
                    am[j] = (float)(0.5 * sqrt(24000.0 / fmax(fv, 1.0)));
                } else { st[j] = 0.0; am[j] = 0.f; }
                loc[j] = s;
                s += st[j];
            }
            double tot = s;
            #pragma unroll
            for (int off = 1; off < 64; off <<= 1) {
                double v = __shfl_up(s, off, 64);
                if (L >= off) s += v;
            }
            double excl = s - tot;
            #pragma unroll
            for (int j = 0; j < 4; ++j) {
                int ft = L * 4 + j;
                if (ft < T_FRAMES) {
                    s_base[ft] = 120.0 * (excl + loc[j]);
                    s_step[ft] = st[j];
                    s_amp[ft]  = am[j];
                }
            }
        }
        __syncthreads();

        if (n < NSAMP) {
            int ft = n / HOPW, k = n - ft * HOPW;
            double st = s_step[ft], bs = s_base[ft];
            double ph  = bs + (double)(k + 1) * st;
            double php = bs + (double)k * st;
            exc[ff * NSAMP + n] = (floor(ph) > floor(php)) ? s_amp[ft] : 0.0f;
        }
        return;
    }

    // =================== embed path (blocks 0..99) ===================
    __shared__ float s_mc[F8][M1];
    __shared__ float s_ap[F8][5];
    __shared__ float s_f0[F8];
    __shared__ float s_h[F8][HID];
    __shared__ float s_ca[F8][CONDW];
    __shared__ float s_cp[F8][CONDW];
    __shared__ float s_mcp[F8][M1];
    __shared__ float s_mca[F8][M1];

    const int R0 = blockIdx.x * F8;

    for (int j = tid; j < F8 * M1; j += 256) s_mc[j / M1][j % M1] = mceps[R0 * M1 + j];
    if (tid < F8 * 5) s_ap[tid / 5][tid % 5] = apdcs[R0 * 5 + tid];
    if (tid < F8)     s_f0[tid] = f0s[R0 + tid];
    __syncthreads();

    {
        float acc[F8];
        const float bias = bm[tid] + ba[tid] + bf[tid];
        #pragma unroll
        for (int r = 0; r < F8; ++r) acc[r] = bias;
        for (int k = 0; k < M1; ++k) {
            float w = Wm[k * HID + tid];
            #pragma unroll
            for (int r = 0; r < F8; ++r) acc[r] = fmaf(s_mc[r][k], w, acc[r]);
        }
        #pragma unroll
        for (int k = 0; k < 5; ++k) {
            float w = Wa[k * HID + tid];
            #pragma unroll
            for (int r = 0; r < F8; ++r) acc[r] = fmaf(s_ap[r][k], w, acc[r]);
        }
        float wf = Wf[tid];
        #pragma unroll
        for (int r = 0; r < F8; ++r) s_h[r][tid] = fmaf(s_f0[r], wf, acc[r]);
    }
    __syncthreads();

    if (tid < CONDW) {
        float aA[F8], aP[F8];
        #pragma unroll
        for (int r = 0; r < F8; ++r) { aA[r] = bpa[tid]; aP[r] = bpp[tid]; }
        for (int k = 0; k < HID; k += 4) {
            float4 h4[F8];
            #pragma unroll
            for (int r = 0; r < F8; ++r) h4[r] = *(const float4*)&s_h[r][k];
            #pragma unroll
            for (int kk = 0; kk < 4; ++kk) {
                float wa = Wpa[(k + kk) * CONDW + tid];
                float wp = Wpp[(k + kk) * CONDW + tid];
                #pragma unroll
                for (int r = 0; r < F8; ++r) {
                    float hv = (&h4[r].x)[kk];
                    aA[r] = fmaf(hv, wa, aA[r]);
                    aP[r] = fmaf(hv, wp, aP[r]);
                }
            }
        }
        #pragma unroll
        for (int r = 0; r < F8; ++r) { s_ca[r][tid] = aA[r]; s_cp[r][tid] = aP[r]; }
    }
    __syncthreads();

    if (tid < M1) {
        const int u = tid;
        float acc[F8];
        #pragma unroll
        for (int r = 0; r < F8; ++r) acc[r] = brp[u];
        for (int k = 0; k < CONDW; k += 4) {
            float4 c4[F8];
            #pragma unroll
            for (int r = 0; r < F8; ++r) c4[r] = *(const float4*)&s_cp[r][k];
            #pragma unroll
            for (int kk = 0; kk < 4; ++kk) {
                float w = Wrp[(k + kk) * M1 + u];
                #pragma unroll
                for (int r = 0; r < F8; ++r) acc[r] = fmaf((&c4[r].x)[kk], w, acc[r]);
            }
        }
        #pragma unroll
        for (int r = 0; r < F8; ++r)
            s_mcp[r][u] = s_mc[r][u] + 0.1f * tanhf(acc[r]);
    } else if (tid >= 64 && tid < 64 + M1) {
        const int u = tid - 64;
        float acc[F8];
        #pragma unroll
        for (int r = 0; r < F8; ++r) acc[r] = bra[u];
        for (int k = 0; k < CONDW; k += 4) {
            float4 c4[F8];
            #pragma unroll
            for (int r = 0; r < F8; ++r) c4[r] = *(const float4*)&s_ca[r][k];
            #pragma unroll
            for (int kk = 0; kk < 4; ++kk) {
                float w = Wra[(k + kk) * M1 + u];
                #pragma unroll
                for (int r = 0; r < F8; ++r) acc[r] = fmaf((&c4[r].x)[kk], w, acc[r]);
            }
        }
        #pragma unroll
        for (int r = 0; r < F8; ++r) {
            float aw = 0.f;
            #pragma unroll
            for (int j = 0; j < 5; ++j) aw = fmaf(s_ap[r][j], Wap[j * M1 + u], aw);
            s_mca[r][u] = s_mc[r][u] + 0.1f * tanhf(acc[r]) + aw;
        }
    }
    __syncthreads();

    if (tid < 16) {
        const int r = tid >> 1, path = tid & 1;
        const int R = R0 + r;
        const int batch = R / T_FRAMES, t = R - batch * T_FRAMES;
        const float* src = path ? s_mca[r] : s_mcp[r];
        float* dst = bcoef + ((path * 4 + batch) * T_FRAMES + t) * M1;
        float prev = src[M1 - 1];
        dst[M1 - 1] = prev;
        for (int m = M1 - 2; m >= 0; --m) {
            prev = src[m] - ALPHA * prev;
            dst[m] = prev;
        }
    }
}

// ---------------------------------------------------------------------------
// DPP helpers. row_shr:N = 0x110|N; row_bcast15 = 0x142.
// ---------------------------------------------------------------------------
template <int CTRL>
__device__ __forceinline__ float rshr(float x) {
    return __int_as_float(
        __builtin_amdgcn_mov_dpp(__float_as_int(x), CTRL, 0xF, 0xF, true));
}
__device__ __forceinline__ float rlane(float x, int l) {
    return __int_as_float(__builtin_amdgcn_readlane(__float_as_int(x), l));
}
// pin a wave-uniform value into a VGPR (DPP-fusable VOP2 forms need vsrc1=VGPR)
__device__ __forceinline__ float vpin(float x) {
    asm("" : "+v"(x));
    return x;
}

// ---------------------------------------------------------------------------
// Samples [ks, ke) of one frame of the lane-parallel dual-filter MLSA scan:
// P on even lanes, A on odd lanes; 8 order-positions x 5 taps per lane;
// Pade rows = tid>>4. X-chain hops 2,3 dropped (weights (-A)^10, (-A)^20 --
// r7, absmax 0.0625 << 0.28). r8 dedup: the boundary value shr2(E4) needed
// by c0 equals shr2(Xt) from the PREVIOUS sample (E4 == Xt_{k-1}), so SiR is
// carried instead of recomputed -- one DPP/sample saved, bit-exact.
// Excitation reads are pipelined one 8-group ahead; yb written as 2x b128.
// ---------------------------------------------------------------------------
__device__ __forceinline__ void run_frame(
    const float* __restrict__ sx, float AB,
    float BP1, float BP2, float BP3, float BP4,
    float B0, float B1, float B2, float B3, float B4,
    float K, float IPw, bool pos0, bool row0, bool parodd,
    float& E0, float& E1, float& E2, float& E3, float& E4, float& SiR,
    float& dlp, float& xin,
    float& m1, float& m2, float& m3, float& m4, float& w0,
    float* __restrict__ yb, int ks, int ke)
{
    const float A   = ALPHA;
    const float AA  = 1.0f - A * A;
    const float A2  = A * A;
    const float mA3 = -(A * A2);
    const float A4  = A2 * A2;
    const float R   = -(A4 * A);     // (-A)^5 : inter-position ratio

    const float Rv   = vpin(R);
    const float IPwv = vpin(IPw);

    // pipelined excitation reads: group k8's data loaded at k8-8's iteration
    float4 g0 = *(const float4*)&sx[ks];
    float4 g1 = *(const float4*)&sx[ks + 4];

    #pragma unroll 1
    for (int k8 = ks; k8 < ke; k8 += 8) {
        const float4 h0 = g0;
        const float4 h1 = g1;
        // issue next group's loads now (last-group overrun lands in LDS pad)
        g0 = *(const float4*)&sx[k8 + 8];
        g1 = *(const float4*)&sx[k8 + 12];
        const float xs[8] = {h0.x, h0.y, h0.z, h0.w, h1.x, h1.y, h1.z, h1.w};
        float yv[8];
        #pragma unroll
        for (int j = 0; j < 8; ++j) {
            float x = xs[j];                           // G pre-folded

            // stage 1 (SPTK mlsadf1), b1-rescaled; y1 = x + 2p
            float na0 = fmaf(A, m1, AA * w0);
            float na1 = fmaf(A, m2, AB * m1);
            float na2 = fmaf(A, m3, AB * m2);
            float na3 = fmaf(A, m4, AB * m3);
            float p = fmaf(na2, BP3, na0 * BP1);
            float q = fmaf(na3, BP4, na1 * BP2);
            float x1 = x + (p - q);
            float y1 = fmaf(2.0f, p, x);
            m1 = na0; m2 = na1; m3 = na2; m4 = na3; w0 = x1;

            // stage 2: 5-tap blocked affine scan over 8 positions (stride 2)
            // boundary value for c0 is SiR from the previous sample (dedup)
            float c0 = fmaf(A, E0, pos0 ? dlp : SiR);
            float c1 = fmaf(A, E1, E0);
            float c2 = fmaf(A, E2, E1);
            float c3 = fmaf(A, E3, E2);
            float c4 = fmaf(A, E4, E3);
            float u0 = c0;
            float u1 = fmaf(-A, u0, c1);
            float u2 = fmaf(-A, u1, c2);
            float u3 = fmaf(-A, u2, c3);
            float u4 = fmaf(-A, u3, c4);
            float X = u4;
            X = fmaf(rshr<0x112>(X), Rv, X);
            // hop2 ((-A)^10) and hop3 ((-A)^20) dropped: << noise floor
            float dl = fmaf(AA, xin, A * dlp);
            float Xt = fmaf(K, dl, X);                 // true last-tap value
            float SiRn = rshr<0x112>(Xt);              // reused as next c0 bnd
            float Si = pos0 ? dl : SiRn;               // true prev-position tap
            float t0 = fmaf(-A,  Si, u0);
            float t1 = fmaf(A2,  Si, u1);
            float t2 = fmaf(mA3, Si, u2);
            float t3 = fmaf(A4,  Si, u3);

            // signed P-weighted fy partial + row prefix -> row totals = +-v2_r
            float fp = t0 * B0;
            fp = fmaf(t1, B1, fp);
            fp = fmaf(t2, B2, fp);
            fp = fmaf(t3, B3, fp);
            fp = fmaf(Xt, B4, fp);
            float S = fp;
            S += rshr<0x112>(S);
            S += rshr<0x114>(S);
            S += rshr<0x118>(S);

            // prev-row same-parity total for rows 1-3
            float Sx  = rshr<0x111>(S);
            float T1m = rshr<0x142>(S)  * IPwv;
            float T0m = rshr<0x142>(Sx) * IPwv;
            float xprev = parodd ? T1m : T0m;

            // glue: per-parity signed 4-row totals; y2 = y1 + 2a (exact)
#if HAVE_PLSWAP
            typedef unsigned u32x2 __attribute__((ext_vector_type(2)));
            u32x2 rr = __builtin_amdgcn_permlane32_swap(
                __float_as_uint(S), __float_as_uint(S), false, false);
            float S2 = __uint_as_float(rr.x) + __uint_as_float(rr.y);
            float aE = rlane(S2, 14), bE = rlane(S2, 30);
            float aO = rlane(S2, 15), bO = rlane(S2, 31);
            float a  = parodd ? aO : aE;
            float bb = parodd ? bO : bE;
            float x2 = y1 + (a + bb);
            yv[j] = fmaf(2.0f, a, y1);
#else
            float s0p = rlane(S, 14), s1p = rlane(S, 30);
            float s2p = rlane(S, 46), s3p = rlane(S, 62);
            float s0a = rlane(S, 15), s1a = rlane(S, 31);
            float s2a = rlane(S, 47), s3a = rlane(S, 63);
            float eP = s0p + s2p, oP = s1p + s3p;
            float eA = s0a + s2a, oA = s1a + s3a;
            float ce = parodd ? eA : eP;
            float co = parodd ? oA : oP;
            float x2 = y1 + (ce + co);
            yv[j] = fmaf(2.0f, ce, y1);
#endif

            // next-sample inputs
            xin = row0 ? x2 : xprev;
            E0 = t0; E1 = t1; E2 = t2; E3 = t3; E4 = Xt; SiR = SiRn;
            dlp = dl;
        }
        // batched yb commit: 2x ds_write_b128 instead of 8x b32
        *(float4*)&yb[k8]     = float4{yv[0], yv[1], yv[2], yv[3]};
        *(float4*)&yb[k8 + 4] = float4{yv[4], yv[5], yv[6], yv[7]};
    }
}

// ---------------------------------------------------------------------------
// Kernel D: MLSA synthesis scan. block = ONE wave = one (96-sample output
// window, batch); P/A on even/odd lanes; P+A combine in LDS -> plain stores.
// Next-frame bcoef + excitation prefetched into registers during the current
// frame's sample loop (double-buffered sexc).
// ---------------------------------------------------------------------------
__global__ __launch_bounds__(64) void mlsa_kernel(
    const float* __restrict__ bcoef, const float* __restrict__ exc,
    float* __restrict__ out)
{
    // row stride 124 floats = 496 B: 16B-aligned, parity rows 28 banks apart
    __shared__ __align__(16) float sexc[2][2][HOPW + 4];   // [buf][par][..]
    __shared__ __align__(16) float ybuf[2][HOPW + 4];

    const int tid = threadIdx.x;
    const int par = tid & 1;              // 0 = periodic, 1 = aperiodic
    const int pos = (tid >> 1) & 7;       // order-position within row
    const int row = tid >> 4;             // Pade tap row
    const int slot = blockIdx.x >> 2;     // 0..249: output window index
    const int b = blockIdx.x & 3;
    const int f = par * 4 + b;
    const bool pos0 = (pos == 0), row0 = (row == 0), parodd = (par != 0);

    const float P1 = 0.4999273f, P2 = 0.1067005f, P3 = 0.00956526f, P4 = 0.0003041358f;
    const float wrow = (row == 0) ? P1 : (row == 1) ? -P2 : (row == 2) ? P3 : -P4;
    const float IPw  = (row == 1) ? (1.f / P1) : (row == 2) ? (-1.f / P2)
                     : (row == 3) ? (1.f / P3) : 0.f;

    const float A = ALPHA;
    const float AAc = 1.0f - A * A;
    const float R = -(A * A * A * A * A);
    float K = R;
    for (int j = 0; j < pos; ++j) K *= R;

    float E0 = 0.f, E1 = 0.f, E2 = 0.f, E3 = 0.f, E4 = 0.f, SiR = 0.f;
    float dlp = 0.f, xin = 0.f;
    float m1 = 0.f, m2 = 0.f, m3 = 0.f, m4 = 0.f, w0 = 0.f;

    float* ybp = ybuf[par];
    const int ja = 5 * pos + 2;
    const int lh = tid >> 1;              // 0..31

    const int o0 = slot * OUTS;           // first output sample
    const int s0 = o0 - WARMS;            // first warm sample (may be < 0)
    const int fA = (s0 <= 0) ? 0 : (s0 / HOPW);
    const int fB = (o0 + OUTS - 1) / HOPW;

    // ---- prologue: load + stage frame fA, compute its constants ----
    {
        const float* bp0 = bcoef + (f * T_FRAMES + fA) * M1;
        const float* ex0 = exc + f * NSAMP + fA * HOPW;
        float G0 = expf(bp0[0]);
        sexc[0][par][lh]      = ex0[lh]      * G0;
        sexc[0][par][lh + 32] = ex0[lh + 32] * G0;
        sexc[0][par][lh + 64] = ex0[lh + 64] * G0;
        if (lh < HOPW - 96) sexc[0][par][lh + 96] = ex0[lh + 96] * G0;
    }
    const float* bpA = bcoef + (f * T_FRAMES + fA) * M1;
    float b1c = bpA[1];
    float AB  = AAc * b1c;
    float BP1 = b1c * P1, BP2 = b1c * P2, BP3 = b1c * P3, BP4 = b1c * P4;
    float B0c = bpA[ja]     * wrow;
    float B1c = bpA[ja + 1] * wrow;
    float B2c = bpA[ja + 2] * wrow;
    float B3c = (pos < 7) ? bpA[ja + 3] * wrow : 0.f;
    float B4c = (pos < 7) ? bpA[ja + 4] * wrow : 0.f;

    int bufi = 0;

    #pragma unroll 1
    for (int ft = fA; ft <= fB; ++ft) {
        const bool hasnext = (ft < fB);
        const int ftn = hasnext ? ft + 1 : ft;      // safe dummy addr if last

        // ---- issue next-frame loads NOW (latency hides under run_frame) ----
        const float* bpn = bcoef + (f * T_FRAMES + ftn) * M1;
        const float* exn = exc + f * NSAMP + ftn * HOPW;
        float n_b0 = bpn[0];
        float n_b1 = bpn[1];
        float n_j0 = bpn[ja], n_j1 = bpn[ja + 1], n_j2 = bpn[ja + 2];
        float n_j3 = (pos < 7) ? bpn[ja + 3] : 0.f;
        float n_j4 = (pos < 7) ? bpn[ja + 4] : 0.f;
        float ne0 = exn[lh];
        float ne1 = exn[lh + 32];
        float ne2 = exn[lh + 64];
        float ne3 = (lh < HOPW - 96) ? exn[lh + 96] : 0.f;

        // runtime sample window of this frame (all bounds multiples of 8)
        int ks = s0 - ft * HOPW; if (ks < 0) ks = 0;
        int ke = o0 + OUTS - ft * HOPW; if (ke > HOPW) ke = HOPW;

        run_frame(sexc[bufi][par], AB, BP1, BP2, BP3, BP4,
                  B0c, B1c, B2c, B3c, B4c, K, IPw, pos0, row0, parodd,
                  E0, E1, E2, E3, E4, SiR, dlp, xin, m1, m2, m3, m4, w0,
                  ybp, ks, ke);

        // store this frame's output window [kout, ke), P+A combined in LDS
        int kout = o0 - ft * HOPW; if (kout < 0) kout = 0;
        if (kout < ke) {
            float* op = out + b * NSAMP + ft * HOPW;
            int i0 = kout + tid;
            if (i0 < ke) op[i0] = ybuf[0][i0] + ybuf[1][i0];
            int i1 = i0 + 64;
            if (i1 < ke) op[i1] = ybuf[0][i1] + ybuf[1][i1];
        }

        // ---- commit prefetched frame: stage + swap constants ----
        if (hasnext) {
            const int nb = bufi ^ 1;
            float Gn = expf(n_b0);
            sexc[nb][par][lh]      = ne0 * Gn;
            sexc[nb][par][lh + 32] = ne1 * Gn;
            sexc[nb][par][lh + 64] = ne2 * Gn;
            if (lh < HOPW - 96) sexc[nb][par][lh + 96] = ne3 * Gn;
            AB  = AAc * n_b1;
            BP1 = n_b1 * P1; BP2 = n_b1 * P2; BP3 = n_b1 * P3; BP4 = n_b1 * P4;
            B0c = n_j0 * wrow;
            B1c = n_j1 * wrow;
            B2c = n_j2 * wrow;
            B3c = n_j3 * wrow;
            B4c = n_j4 * wrow;
            bufi = nb;
        }
    }
}

// ---------------------------------------------------------------------------
extern "C" void kernel_launch(void* const* d_in, const int* in_sizes, int n_in,
                              void* d_out, int out_size, void* d_ws, size_t ws_size,
                              hipStream_t stream) {
    const float* mceps = (const float*)d_in[0];
    const float* apdcs = (const float*)d_in[1];
    const float* f0s   = (const float*)d_in[2];
    const float* noise = (const float*)d_in[3];
    const float* Wm  = (const float*)d_in[4];
    const float* bm  = (const float*)d_in[5];
    const float* Wa  = (const float*)d_in[6];
    const float* ba  = (const float*)d_in[7];
    const float* Wf  = (const float*)d_in[8];
    const float* bf  = (const float*)d_in[9];
    const float* Wpa = (const float*)d_in[10];
    const float* bpa = (const float*)d_in[11];
    const float* Wpp = (const float*)d_in[12];
    const float* bpp = (const float*)d_in[13];
    const float* Wrp = (const float*)d_in[14];
    const float* brp = (const float*)d_in[15];
    const float* Wra = (const float*)d_in[16];
    const float* bra = (const float*)d_in[17];
    const float* Wap = (const float*)d_in[18];
    float* out = (float*)d_out;

    char* ws = (char*)d_ws;
    float* bcoef = (float*)(ws + 0);           // 256000 B
    float* exc   = (float*)(ws + 256000);      // 768000 B

    prep_kernel<<<dim3(EMB_BLOCKS + 8 * BPF), dim3(256), 0, stream>>>(
        mceps, apdcs, f0s, noise, Wm, bm, Wa, ba, Wf, bf,
        Wpa, bpa, Wpp, bpp, Wrp, brp, Wra, bra, Wap, bcoef, exc);

    // every output sample owned by exactly one block -> no memset, no atomics
    mlsa_kernel<<<dim3(SLOTS * 4), dim3(64), 0, stream>>>(bcoef, exc, out);
}